// Round 6
// baseline (341.502 us; speedup 1.0000x reference)
//
#include <hip/hip_runtime.h>

// ---------------------------------------------------------------------------
// AttentionLayer: out = softmax((xWq+bq)(xWk+bk)^T/8 + mask) (xWv+bv)
// B=4, S=2048, D=1024, H=16, Dh=64.  All-bf16 MFMA pipeline, fp32 accum.
// R20: ZERO-LDS / ZERO-BARRIER attn.  K/V per bh (512KB) is L2-resident
//      (16 blocks of one bh share an XCD); the LDS staging hop was pure
//      overhead (catalog common-mistake #7: dropping V-staging at L2-fit
//      was +26%).  K/V/Q fragments load DIRECTLY from global into MFMA
//      operand regs (exact addressing derived from the verified swizzle
//      chain; qf-direct already proven in R17/R18).  No __shared__, no
//      __syncthreads => waves free-run, staging VALU/LDS work deleted.
// LAWS: R19 diet: arch 80 + ~48 acc = 128 total still 2 waves/SIMD (band
//      boundary exclusive) => occupancy structurally capped; CLOSED.
//      R15 reg-staging K/V SPILLS; R16 LDS dbuf -5%; R17 T15 -3%;
//      R18 wide-Q SPILLS (-32%); 7 scheduling variants null/neg.
//      bound(256,4)=>spill; reuse=2=>spill.
//      => remaining levers: less total pipe work, less lockstep (this).
// ---------------------------------------------------------------------------

typedef __attribute__((ext_vector_type(8))) short bf16x8;
typedef __attribute__((ext_vector_type(4))) float f32x4;
typedef __attribute__((ext_vector_type(16))) float f32x16;

#define LOG2E 1.4426950408889634f

__device__ __forceinline__ ushort f2bf(float f) {
  union { float f; unsigned int u; } x; x.f = f;
  unsigned int r = x.u + 0x7fffu + ((x.u >> 16) & 1u);   // RNE
  return (ushort)(r >> 16);
}

// async global->LDS, 16B per lane; LDS dest = wave-uniform base + lane*16
__device__ __forceinline__ void gload16(const ushort* g, ushort* l) {
  __builtin_amdgcn_global_load_lds(
      (__attribute__((address_space(1))) unsigned int*)(g),
      (__attribute__((address_space(3))) unsigned int*)(l), 16, 0, 0);
}

// ---------------------------------------------------------------------------
// prep: blocks 0..8191 = x->bf16; 8192..11263 = W transpose; 11264 = mask scan
__global__ __launch_bounds__(256) void prep(
    const float* __restrict__ x, ushort* __restrict__ xb,
    const float* __restrict__ Wq, const float* __restrict__ Wk,
    const float* __restrict__ Wv, ushort* __restrict__ WT,
    const int* __restrict__ mask, int* __restrict__ flagw) {
  __shared__ float tile[32][33];
  __shared__ int accum[64];
  const int blk = blockIdx.x, t = threadIdx.x;
  if (blk < 8192) {
    int i = blk * 256 + t;
    float4 v = ((const float4*)x)[i];
    ushort4 o;
    o.x = f2bf(v.x); o.y = f2bf(v.y); o.z = f2bf(v.z); o.w = f2bf(v.w);
    ((ushort4*)xb)[i] = o;
  } else if (blk < 11264) {
    int bb = blk - 8192;
    int z = bb >> 10, rem = bb & 1023, db = rem >> 5, nb = rem & 31;
    const float* W = (z == 0) ? Wq : ((z == 1) ? Wk : Wv);
    int tx = t & 31, ty = t >> 5;   // 32 x 8
#pragma unroll
    for (int i = 0; i < 4; i++) {
      int dl = ty + i * 8;
      tile[dl][tx] = W[(size_t)(db * 32 + dl) * 1024 + nb * 32 + tx];
    }
    __syncthreads();
#pragma unroll
    for (int i = 0; i < 4; i++) {
      int nl = ty + i * 8;
      WT[(size_t)(z * 1024 + nb * 32 + nl) * 1024 + db * 32 + tx] = f2bf(tile[tx][nl]);
    }
  } else {
    if (t < 64) accum[t] = 0;
    __syncthreads();
    int p = t >> 2, j = t & 3;          // p = b*16+kt
    int base = p * 128 + j * 32;
    int s = 0;
#pragma unroll
    for (int i = 0; i < 8; i++) {
      int4 v = *(const int4*)(mask + base + i * 4);
      s += v.x + v.y + v.z + v.w;
    }
    atomicAdd(&accum[p], s);
    __syncthreads();
    if (t < 4) {
      int w = 0;
#pragma unroll
      for (int kt = 0; kt < 16; kt++)
        if (accum[t * 16 + kt] != 128) w |= (1 << kt);
      flagw[t] = w;
    }
  }
}

// ---------------------------------------------------------------------------
// fused QKV GEMM, m97 structure + early-issue staging (R8 version, (256,2)).
// blocks 0..1023: mode0 (Q,K: M=8192 N=2048); 1024..1535: mode1 (V^T).
__global__ __launch_bounds__(256, 2) void gemm_qkv(
    const ushort* __restrict__ xb, const ushort* __restrict__ WT,
    const float* __restrict__ bq, const float* __restrict__ bk,
    const float* __restrict__ bv, ushort* __restrict__ Qg,
    ushort* __restrict__ Kg, ushort* __restrict__ VTg) {
  __shared__ __align__(16) ushort As[128 * 64];
  __shared__ __align__(16) ushort Bs[128 * 64];
  const int t = threadIdx.x, wid = t >> 6, lane = t & 63;
  const int blk = blockIdx.x;
  int mode, mb, nb;
  const ushort *A, *B;
  if (blk < 1024) {
    mode = 0;
    int lin2 = (blk & 7) * 128 + (blk >> 3);   // XCD owns 8 mb-panels
    nb = lin2 & 15; mb = lin2 >> 4;
    A = xb; B = WT;
  } else {
    mode = 1;
    int l = blk - 1024;
    int lin2 = (l & 7) * 64 + (l >> 3);        // XCD owns 8 nb-panels
    mb = lin2 & 7; nb = lin2 >> 3;
    A = WT + (size_t)2048 * 1024; B = xb;
  }
  const ushort* Ab = A + (size_t)mb * 128 * 1024;
  const ushort* Bb = B + (size_t)nb * 128 * 1024;
  const int wr = wid >> 1, wc = wid & 1;

  f32x4 acc[4][4] = {};

  const int srow = lane >> 3;              // 0..7 row-in-8
  const int schunk = (lane & 7) ^ srow;    // pre-swizzled source chunk

  // prologue: issue stage(0)
#pragma unroll
  for (int i = 0; i < 4; i++) {
    int blki = i * 4 + wid;
    int row = blki * 8 + srow;
    int ldso = __builtin_amdgcn_readfirstlane(blki * 512);
    gload16(Ab + (size_t)row * 1024 + schunk * 8, As + ldso);
    gload16(Bb + (size_t)row * 1024 + schunk * 8, Bs + ldso);
  }

  for (int kt = 0; kt < 16; ++kt) {
    __syncthreads();                       // (1) stage(kt) arrived

    bf16x8 af[2][4], bf[2][4];
#pragma unroll
    for (int ks = 0; ks < 2; ks++) {
#pragma unroll
      for (int m = 0; m < 4; m++) {
        int row = wr * 64 + m * 16 + (lane & 15);
        int slot = (ks * 4 + (lane >> 4)) ^ (row & 7);
        af[ks][m] = *(const bf16x8*)(As + row * 64 + slot * 8);
      }
#pragma unroll
      for (int n = 0; n < 4; n++) {
        int row = wc * 64 + n * 16 + (lane & 15);
        int slot = (ks * 4 + (lane >> 4)) ^ (row & 7);
        bf[ks][n] = *(const bf16x8*)(Bs + row * 64 + slot * 8);
      }
    }
    __syncthreads();                       // (2) all fragment reads in regs

    if (kt < 15) {
      const int kof = (kt + 1) * 64 + schunk * 8;
#pragma unroll
      for (int i = 0; i < 4; i++) {
        int blki = i * 4 + wid;
        int row = blki * 8 + srow;
        int ldso = __builtin_amdgcn_readfirstlane(blki * 512);
        gload16(Ab + (size_t)row * 1024 + kof, As + ldso);
        gload16(Bb + (size_t)row * 1024 + kof, Bs + ldso);
      }
    }

#pragma unroll
    for (int ks = 0; ks < 2; ks++)
#pragma unroll
      for (int m = 0; m < 4; m++)
#pragma unroll
        for (int n = 0; n < 4; n++)
          acc[m][n] = __builtin_amdgcn_mfma_f32_16x16x32_bf16(
              af[ks][m], bf[ks][n], acc[m][n], 0, 0, 0);
  }

  // epilogue
#pragma unroll
  for (int m = 0; m < 4; m++) {
#pragma unroll
    for (int n = 0; n < 4; n++) {
      if (mode == 0) {
        int col = nb * 128 + wc * 64 + n * 16 + (lane & 15);  // n: [Q|K] 0..2047
        int wq = col >> 10;                                   // 0=Q 1=K
        float bs = wq ? bk[col & 1023] : bq[col & 1023];
        float scale = wq ? 1.0f : (0.125f * LOG2E);           // fold log2e into Q
        ushort* dst = wq ? Kg : Qg;
        int h = (col >> 6) & 15, d = col & 63;
#pragma unroll
        for (int r = 0; r < 4; r++) {
          int row = mb * 128 + wr * 64 + m * 16 + (lane >> 4) * 4 + r;  // b*2048+s
          int b = row >> 11, s = row & 2047;
          float v = (acc[m][n][r] + bs) * scale;
          dst[((size_t)((b << 4) + h) * 2048 + s) * 64 + d] = f2bf(v);
        }
      } else {
        int col = nb * 128 + wc * 64 + n * 16 + (lane & 15);  // m-index: b*2048+s
        int b = col >> 11, s = col & 2047;
#pragma unroll
        for (int r = 0; r < 4; r++) {
          int p = mb * 128 + wr * 64 + m * 16 + (lane >> 4) * 4 + r;  // h*64+d
          float v = acc[m][n][r] + bv[p];
          int h = p >> 6, d = p & 63;
          VTg[((size_t)((b << 4) + h) * 64 + d) * 2048 + s] = f2bf(v);
        }
      }
    }
  }
}

// ---------------------------------------------------------------------------
// Flash attention (R20 body): ZERO-LDS, ZERO-BARRIER.  All MFMA operands
// load directly from global (L1/L2-resident tiles).  Swapped-operand 32x32
// MFMA, per-kb fused QK->exp2->pack->PV, max-free softmax, XCD chunking.
// Operand addressing (exact, from verified fragment layouts):
//   kf[ds] = Kbh[(kt*128+kb*32+l31)*64 + ds*16+hi*8]      (A-op of QK)
//   qf[ds] = Qbh[(qb*128+wid*32+l31)*64 + ds*16+hi*8]     (B-op of QK)
//   vf     = Vbh[(df*32+l31)*2048 + kt*128+kb*32+w2*16+hi*8]  (A-op of PV)
//   mask adds: lane-direct int4 at [kt*128+kb*32+qd*8+hi*4]   (msk only)
__global__ __launch_bounds__(256, 3) void attn_kernel(
    const ushort* __restrict__ Qg, const ushort* __restrict__ Kg,
    const ushort* __restrict__ VTg, const int* __restrict__ mask,
    const int* __restrict__ flagw, float* __restrict__ out) {
  const int t = threadIdx.x, wid = t >> 6, lane = t & 63;
  const int l31 = lane & 31, hi = lane >> 5;
  const int lin = blockIdx.x;
  const int lin2 = (lin & 7) * 128 + (lin >> 3);   // bijective XCD chunking
  const int qb = lin2 & 15, bh = lin2 >> 4;
  const int b = bh >> 4, h = bh & 15;
  const ushort* Kbh = Kg + (size_t)bh * 2048 * 64;
  const ushort* Vbh = VTg + (size_t)bh * 64 * 2048;

  // ---- qf direct from global ----
  bf16x8 qf[4];
  {
    const ushort* qrow =
        Qg + ((size_t)bh * 2048 + qb * 128 + wid * 32 + l31) * 64 + hi * 8;
#pragma unroll
    for (int ds = 0; ds < 4; ds++)
      qf[ds] = *(const bf16x8*)(qrow + ds * 16);
  }
  const int fb = flagw[b];            // per-tile mask bits (uniform)

  // ---- per-lane operand base pointers ----
  const ushort* kl = Kbh + l31 * 64 + hi * 8;            // + kt*8192 + kb*2048 + ds*16
  const ushort* vl = Vbh + (size_t)l31 * 2048 + hi * 8;  // + df*65536 + kt*128 + kb*32 + w2*16
  const int* ml = mask + b * 2048 + hi * 4;              // + kt*128 + kb*32 + qd*8

  f32x16 cacc[2] = {};
  float l0 = 0.f, l1 = 0.f;           // persistent psum chains

  for (int kt = 0; kt < 16; ++kt) {
    const ushort* kp = kl + kt * 8192;
    const ushort* vp = vl + kt * 128;
    const bool msk = ((fb >> kt) & 1) != 0;

    // ---- per-kb fused: QK (4 MFMA) -> exp2 -> pack -> PV (4 MFMA) ----
#pragma unroll
    for (int kb = 0; kb < 4; kb++) {
      const ushort* kq = kp + kb * 2048;
      const f32x16 zz = {};
      __builtin_amdgcn_s_setprio(1);
      bf16x8 kf0 = *(const bf16x8*)(kq);
      f32x16 a = __builtin_amdgcn_mfma_f32_32x32x16_bf16(kf0, qf[0], zz, 0, 0, 0);
      bf16x8 kf1 = *(const bf16x8*)(kq + 16);
      a = __builtin_amdgcn_mfma_f32_32x32x16_bf16(kf1, qf[1], a, 0, 0, 0);
      bf16x8 kf2 = *(const bf16x8*)(kq + 32);
      a = __builtin_amdgcn_mfma_f32_32x32x16_bf16(kf2, qf[2], a, 0, 0, 0);
      bf16x8 kf3 = *(const bf16x8*)(kq + 48);
      a = __builtin_amdgcn_mfma_f32_32x32x16_bf16(kf3, qf[3], a, 0, 0, 0);
      __builtin_amdgcn_s_setprio(0);

      if (msk) {
        const int* mb_ = ml + kt * 128 + kb * 32;
#pragma unroll
        for (int qd = 0; qd < 4; qd++) {
          int4 mv = *(const int4*)(mb_ + qd * 8);
          a[qd * 4 + 0] += (1.0f - (float)mv.x) * (-10000.0f * LOG2E);
          a[qd * 4 + 1] += (1.0f - (float)mv.y) * (-10000.0f * LOG2E);
          a[qd * 4 + 2] += (1.0f - (float)mv.z) * (-10000.0f * LOG2E);
          a[qd * 4 + 3] += (1.0f - (float)mv.w) * (-10000.0f * LOG2E);
        }
      }

#pragma unroll
      for (int w2 = 0; w2 < 2; w2++) {
        const int o = w2 * 8;
        float e0 = __builtin_amdgcn_exp2f(a[o + 0]);
        float e1 = __builtin_amdgcn_exp2f(a[o + 1]);
        float e2 = __builtin_amdgcn_exp2f(a[o + 2]);
        float e3 = __builtin_amdgcn_exp2f(a[o + 3]);
        float e4 = __builtin_amdgcn_exp2f(a[o + 4]);
        float e5 = __builtin_amdgcn_exp2f(a[o + 5]);
        float e6 = __builtin_amdgcn_exp2f(a[o + 6]);
        float e7 = __builtin_amdgcn_exp2f(a[o + 7]);
        l0 += e0; l1 += e1; l0 += e2; l1 += e3;
        l0 += e4; l1 += e5; l0 += e6; l1 += e7;
        unsigned a0, a1, b0, b1;
        asm("v_cvt_pk_bf16_f32 %0, %1, %2" : "=v"(a0) : "v"(e0), "v"(e1));
        asm("v_cvt_pk_bf16_f32 %0, %1, %2" : "=v"(a1) : "v"(e2), "v"(e3));
        asm("v_cvt_pk_bf16_f32 %0, %1, %2" : "=v"(b0) : "v"(e4), "v"(e5));
        asm("v_cvt_pk_bf16_f32 %0, %1, %2" : "=v"(b1) : "v"(e6), "v"(e7));
        asm("v_permlane32_swap_b32 %0, %1" : "+v"(a0), "+v"(b0));
        asm("v_permlane32_swap_b32 %0, %1" : "+v"(a1), "+v"(b1));
        union { unsigned u[4]; bf16x8 v8; } pu;
        pu.u[0] = a0; pu.u[1] = a1; pu.u[2] = b0; pu.u[3] = b1;
        bf16x8 pf = pu.v8;
        __builtin_amdgcn_s_setprio(1);
#pragma unroll
        for (int df = 0; df < 2; df++) {
          bf16x8 vf = *(const bf16x8*)(vp + df * 65536 + kb * 32 + w2 * 16);
          cacc[df] = __builtin_amdgcn_mfma_f32_32x32x16_bf16(vf, pf, cacc[df], 0, 0, 0);
        }
        __builtin_amdgcn_s_setprio(0);
      }
    }
  }

  // ---- epilogue: l = in-lane chains + cross-hi partner; ctx^T / l ----
  float lrun = l0 + l1;
  lrun += __shfl_xor(lrun, 32);
  float linv = 1.0f / lrun;
  int qg = qb * 128 + wid * 32 + l31;
  float* op = out + ((size_t)(b * 2048 + qg)) * 1024 + h * 64;
#pragma unroll
  for (int df = 0; df < 2; df++)
#pragma unroll
    for (int qd = 0; qd < 4; qd++) {
      f32x4 v;
      v[0] = cacc[df][qd * 4 + 0] * linv;
      v[1] = cacc[df][qd * 4 + 1] * linv;
      v[2] = cacc[df][qd * 4 + 2] * linv;
      v[3] = cacc[df][qd * 4 + 3] * linv;
      *(f32x4*)(op + df * 32 + qd * 8 + hi * 4) = v;
    }
}

// ---------------------------------------------------------------------------
extern "C" void kernel_launch(void* const* d_in, const int* in_sizes, int n_in,
                              void* d_out, int out_size, void* d_ws, size_t ws_size,
                              hipStream_t stream) {
  const float* x  = (const float*)d_in[0];
  const int* mask = (const int*)d_in[1];
  const float* Wq = (const float*)d_in[2];
  const float* bq = (const float*)d_in[3];
  const float* Wk = (const float*)d_in[4];
  const float* bk = (const float*)d_in[5];
  const float* Wv = (const float*)d_in[6];
  const float* bv = (const float*)d_in[7];
  float* out = (float*)d_out;

  char* ws = (char*)d_ws;
  ushort* xb  = (ushort*)(ws);                                  // 16 MB
  ushort* WT  = (ushort*)(ws + (size_t)16777216);               // 6 MB
  ushort* Qg  = (ushort*)(ws + (size_t)23068672);               // 16 MB
  ushort* Kg  = (ushort*)(ws + (size_t)39845888);               // 16 MB
  ushort* VTg = (ushort*)(ws + (size_t)56623104);               // 16 MB
  int*    flg = (int*)(ws + (size_t)73400320);                  // 16 B

  prep<<<dim3(11265), dim3(256), 0, stream>>>(x, xb, Wq, Wk, Wv, WT, mask, flg);
  gemm_qkv<<<dim3(1536), dim3(256), 0, stream>>>(xb, WT, bq, bk, bv, Qg, Kg, VTg);
  attn_kernel<<<dim3(1024), dim3(256), 0, stream>>>(Qg, Kg, VTg, mask, flg, out);
}

// Round 7
// 162.846 us; speedup vs baseline: 2.0971x; 2.0971x over previous
//
#include <hip/hip_runtime.h>

// ---------------------------------------------------------------------------
// AttentionLayer: out = softmax((xWq+bq)(xWk+bk)^T/8 + mask) (xWv+bv)
// B=4, S=2048, D=1024, H=16, Dh=64.  All-bf16 MFMA pipeline, fp32 accum.
// R21: KVBLK 128 -> 256 in attn (single-buffer, same 2-barrier structure).
//      Halves per-block phase fixed costs: barriers 32->16, vmcnt drains
//      16->8, staging rounds 16->8 (16 issues each, deeper queue).  LDS
//      33->65KB is free: residency is register-capped at 2 blocks/CU
//      (R19 law), 2x65=130 <= 160KB.  Swizzle algebra survives intact:
//      K pair-interleave key pr&15 = 4*wid+pr_l stays i-independent
//      (16i = 0 mod 16); V slot key gains only an (i&1) XOR-8 term
//      (ovle/ovlo lane constants).  Compute stream byte-identical per kb.
// LAWS: R19 diet landed (80 VGPR) but 128-total still 2 waves/SIMD =>
//      occupancy CLOSED.  R20 zero-LDS = 3x WORSE (L2-hit latency in the
//      MFMA chain, no TLP cover at 2 waves/SIMD) => LDS staging is
//      load-bearing.  R15 reg-staging SPILLS; R16 LDS dbuf -5%; R17 T15
//      -3%; R18 wide-Q SPILLS -32%; 7 scheduling variants null/neg;
//      bound(256,4)=>spill; reuse=2=>spill.  GEMM ~1100TF already (L2-
//      resident K=1024 panels); 8-phase port quantizes to 2 half-empty
//      rounds => <=5us upside, closed.
// ---------------------------------------------------------------------------

typedef __attribute__((ext_vector_type(8))) short bf16x8;
typedef __attribute__((ext_vector_type(4))) float f32x4;
typedef __attribute__((ext_vector_type(16))) float f32x16;

#define LOG2E 1.4426950408889634f

__device__ __forceinline__ ushort f2bf(float f) {
  union { float f; unsigned int u; } x; x.f = f;
  unsigned int r = x.u + 0x7fffu + ((x.u >> 16) & 1u);   // RNE
  return (ushort)(r >> 16);
}

// async global->LDS, 16B per lane; LDS dest = wave-uniform base + lane*16
__device__ __forceinline__ void gload16(const ushort* g, ushort* l) {
  __builtin_amdgcn_global_load_lds(
      (__attribute__((address_space(1))) unsigned int*)(g),
      (__attribute__((address_space(3))) unsigned int*)(l), 16, 0, 0);
}

// ---------------------------------------------------------------------------
// prep: blocks 0..8191 = x->bf16; 8192..11263 = W transpose; 11264 = mask scan
__global__ __launch_bounds__(256) void prep(
    const float* __restrict__ x, ushort* __restrict__ xb,
    const float* __restrict__ Wq, const float* __restrict__ Wk,
    const float* __restrict__ Wv, ushort* __restrict__ WT,
    const int* __restrict__ mask, int* __restrict__ flagw) {
  __shared__ float tile[32][33];
  __shared__ int accum[64];
  const int blk = blockIdx.x, t = threadIdx.x;
  if (blk < 8192) {
    int i = blk * 256 + t;
    float4 v = ((const float4*)x)[i];
    ushort4 o;
    o.x = f2bf(v.x); o.y = f2bf(v.y); o.z = f2bf(v.z); o.w = f2bf(v.w);
    ((ushort4*)xb)[i] = o;
  } else if (blk < 11264) {
    int bb = blk - 8192;
    int z = bb >> 10, rem = bb & 1023, db = rem >> 5, nb = rem & 31;
    const float* W = (z == 0) ? Wq : ((z == 1) ? Wk : Wv);
    int tx = t & 31, ty = t >> 5;   // 32 x 8
#pragma unroll
    for (int i = 0; i < 4; i++) {
      int dl = ty + i * 8;
      tile[dl][tx] = W[(size_t)(db * 32 + dl) * 1024 + nb * 32 + tx];
    }
    __syncthreads();
#pragma unroll
    for (int i = 0; i < 4; i++) {
      int nl = ty + i * 8;
      WT[(size_t)(z * 1024 + nb * 32 + nl) * 1024 + db * 32 + tx] = f2bf(tile[tx][nl]);
    }
  } else {
    if (t < 64) accum[t] = 0;
    __syncthreads();
    int p = t >> 2, j = t & 3;          // p = b*16+kt
    int base = p * 128 + j * 32;
    int s = 0;
#pragma unroll
    for (int i = 0; i < 8; i++) {
      int4 v = *(const int4*)(mask + base + i * 4);
      s += v.x + v.y + v.z + v.w;
    }
    atomicAdd(&accum[p], s);
    __syncthreads();
    if (t < 4) {
      int w = 0;
#pragma unroll
      for (int kt = 0; kt < 16; kt++)
        if (accum[t * 16 + kt] != 128) w |= (1 << kt);
      flagw[t] = w;
    }
  }
}

// ---------------------------------------------------------------------------
// fused QKV GEMM, m97 structure + early-issue staging (R8 version, (256,2)).
// blocks 0..1023: mode0 (Q,K: M=8192 N=2048); 1024..1535: mode1 (V^T).
__global__ __launch_bounds__(256, 2) void gemm_qkv(
    const ushort* __restrict__ xb, const ushort* __restrict__ WT,
    const float* __restrict__ bq, const float* __restrict__ bk,
    const float* __restrict__ bv, ushort* __restrict__ Qg,
    ushort* __restrict__ Kg, ushort* __restrict__ VTg) {
  __shared__ __align__(16) ushort As[128 * 64];
  __shared__ __align__(16) ushort Bs[128 * 64];
  const int t = threadIdx.x, wid = t >> 6, lane = t & 63;
  const int blk = blockIdx.x;
  int mode, mb, nb;
  const ushort *A, *B;
  if (blk < 1024) {
    mode = 0;
    int lin2 = (blk & 7) * 128 + (blk >> 3);   // XCD owns 8 mb-panels
    nb = lin2 & 15; mb = lin2 >> 4;
    A = xb; B = WT;
  } else {
    mode = 1;
    int l = blk - 1024;
    int lin2 = (l & 7) * 64 + (l >> 3);        // XCD owns 8 nb-panels
    mb = lin2 & 7; nb = lin2 >> 3;
    A = WT + (size_t)2048 * 1024; B = xb;
  }
  const ushort* Ab = A + (size_t)mb * 128 * 1024;
  const ushort* Bb = B + (size_t)nb * 128 * 1024;
  const int wr = wid >> 1, wc = wid & 1;

  f32x4 acc[4][4] = {};

  const int srow = lane >> 3;              // 0..7 row-in-8
  const int schunk = (lane & 7) ^ srow;    // pre-swizzled source chunk

  // prologue: issue stage(0)
#pragma unroll
  for (int i = 0; i < 4; i++) {
    int blki = i * 4 + wid;
    int row = blki * 8 + srow;
    int ldso = __builtin_amdgcn_readfirstlane(blki * 512);
    gload16(Ab + (size_t)row * 1024 + schunk * 8, As + ldso);
    gload16(Bb + (size_t)row * 1024 + schunk * 8, Bs + ldso);
  }

  for (int kt = 0; kt < 16; ++kt) {
    __syncthreads();                       // (1) stage(kt) arrived

    bf16x8 af[2][4], bf[2][4];
#pragma unroll
    for (int ks = 0; ks < 2; ks++) {
#pragma unroll
      for (int m = 0; m < 4; m++) {
        int row = wr * 64 + m * 16 + (lane & 15);
        int slot = (ks * 4 + (lane >> 4)) ^ (row & 7);
        af[ks][m] = *(const bf16x8*)(As + row * 64 + slot * 8);
      }
#pragma unroll
      for (int n = 0; n < 4; n++) {
        int row = wc * 64 + n * 16 + (lane & 15);
        int slot = (ks * 4 + (lane >> 4)) ^ (row & 7);
        bf[ks][n] = *(const bf16x8*)(Bs + row * 64 + slot * 8);
      }
    }
    __syncthreads();                       // (2) all fragment reads in regs

    if (kt < 15) {
      const int kof = (kt + 1) * 64 + schunk * 8;
#pragma unroll
      for (int i = 0; i < 4; i++) {
        int blki = i * 4 + wid;
        int row = blki * 8 + srow;
        int ldso = __builtin_amdgcn_readfirstlane(blki * 512);
        gload16(Ab + (size_t)row * 1024 + kof, As + ldso);
        gload16(Bb + (size_t)row * 1024 + kof, Bs + ldso);
      }
    }

#pragma unroll
    for (int ks = 0; ks < 2; ks++)
#pragma unroll
      for (int m = 0; m < 4; m++)
#pragma unroll
        for (int n = 0; n < 4; n++)
          acc[m][n] = __builtin_amdgcn_mfma_f32_16x16x32_bf16(
              af[ks][m], bf[ks][n], acc[m][n], 0, 0, 0);
  }

  // epilogue
#pragma unroll
  for (int m = 0; m < 4; m++) {
#pragma unroll
    for (int n = 0; n < 4; n++) {
      if (mode == 0) {
        int col = nb * 128 + wc * 64 + n * 16 + (lane & 15);  // n: [Q|K] 0..2047
        int wq = col >> 10;                                   // 0=Q 1=K
        float bs = wq ? bk[col & 1023] : bq[col & 1023];
        float scale = wq ? 1.0f : (0.125f * LOG2E);           // fold log2e into Q
        ushort* dst = wq ? Kg : Qg;
        int h = (col >> 6) & 15, d = col & 63;
#pragma unroll
        for (int r = 0; r < 4; r++) {
          int row = mb * 128 + wr * 64 + m * 16 + (lane >> 4) * 4 + r;  // b*2048+s
          int b = row >> 11, s = row & 2047;
          float v = (acc[m][n][r] + bs) * scale;
          dst[((size_t)((b << 4) + h) * 2048 + s) * 64 + d] = f2bf(v);
        }
      } else {
        int col = nb * 128 + wc * 64 + n * 16 + (lane & 15);  // m-index: b*2048+s
        int b = col >> 11, s = col & 2047;
#pragma unroll
        for (int r = 0; r < 4; r++) {
          int p = mb * 128 + wr * 64 + m * 16 + (lane >> 4) * 4 + r;  // h*64+d
          float v = acc[m][n][r] + bv[p];
          int h = p >> 6, d = p & 63;
          VTg[((size_t)((b << 4) + h) * 64 + d) * 2048 + s] = f2bf(v);
        }
      }
    }
  }
}

// ---------------------------------------------------------------------------
// Flash attention (R21 = R19 body at KVBLK=256): swapped-operand 32x32 MFMA,
// single-buffer 2-phase loop, per-kb fused QK->exp->pack->PV, max-free
// softmax, XCD swizzle, K/Q pair-interleave LDS mapping.
// K tile 256x64 pair-interleaved into 128 phys rows x 256B (32KB);
// V tile 64x256 rows of 512B, 32 16B-slots, XOR key (d&15) (32KB).
// 8 kt phases of 8 kb blocks; 16 staging issues/wave/phase.
__global__ __launch_bounds__(256, 3) void attn_kernel(
    const ushort* __restrict__ Qg, const ushort* __restrict__ Kg,
    const ushort* __restrict__ VTg, const int* __restrict__ mask,
    const int* __restrict__ flagw, float* __restrict__ out) {
  __shared__ __align__(16) ushort Ks[128 * 128];  // 32KB: 128 phys rows x 256B
  __shared__ __align__(16) ushort Vs[64 * 256];   // 32KB: 64 rows x 512B
  __shared__ float maddv[256];

  const int t = threadIdx.x, wid = t >> 6, lane = t & 63;
  const int l31 = lane & 31, hi = lane >> 5;
  const int lin = blockIdx.x;
  const int lin2 = (lin & 7) * 128 + (lin >> 3);   // bijective XCD chunking
  const int qb = lin2 & 15, bh = lin2 >> 4;
  const int b = bh >> 4, h = bh & 15;
  const ushort* Qbh = Qg + ((size_t)bh * 2048 + qb * 128) * 64;
  const ushort* Kbh = Kg + (size_t)bh * 2048 * 64;
  const ushort* Vbh = VTg + (size_t)bh * 64 * 2048;

  // ---- K staging lane constants (pair-interleave inverse map) ----
  // pr = blki*4 + pr_l, blki = i*4+wid => pr&15 = 4*wid+pr_l (i-indep)
  const int pr_l = lane >> 4;                 // 0..3 within issue
  const int s_l = lane & 15;
  const int spk = s_l ^ (4 * wid + pr_l);
  const int okl = 128 * pr_l + (spk >> 3) * 64 + (spk & 7) * 8;
  // ---- V staging lane constants: d = blki*2 + d_l; 32 slots/row ----
  // d&15 = (8i + 2*wid + d_l)&15 = (2*wid+d_l) | 8*(i&1)  (no carry)
  const int d_l = lane >> 5;                  // 0..1
  const int c_s = lane & 31;                  // 0..31
  const int cvg0 = c_s ^ (2 * wid + d_l);
  const int ovle = 2048 * d_l + cvg0 * 8;             // even i
  const int ovlo = 2048 * d_l + (cvg0 ^ 8) * 8;       // odd i

  // ---- fragment-read lane constants ----
  const int prq = l31 >> 1;                   // phys row in 16-row group (0..15)
  const int hq8 = (l31 & 1) << 3;             // halfq<<3

  // ---- prologue: stage Q tile [128][64] into Ks (pair-interleaved) ----
#pragma unroll
  for (int i = 0; i < 4; i++) {
    int blki = i * 4 + wid;
    int ldso = __builtin_amdgcn_readfirstlane(blki * 512);
    gload16(Qbh + blki * 512 + okl, Ks + ldso);
  }
  const int fb = flagw[b];            // per-128-tile mask bits (uniform)
  __syncthreads();
  bf16x8 qf[4];
  {
    const ushort* qbase = Ks + (wid * 16 + prq) * 128;   // phys row *256B
#pragma unroll
    for (int ds = 0; ds < 4; ds++) {
      int slot = ((ds * 2 + hi) | hq8) ^ prq;
      qf[ds] = *(const bf16x8*)(qbase + slot * 8);
    }
  }
  __syncthreads();                    // qf reads done before Ks restage

  f32x16 cacc[2] = {};
  float l0 = 0.f, l1 = 0.f;           // persistent psum chains

  for (int kt = 0; kt < 8; ++kt) {    // 8 phases of 256 k-rows
    // ---- stage K (pair-interleaved, 8 issues) and VT (8 issues) ----
#pragma unroll
    for (int i = 0; i < 8; i++) {
      int blki = i * 4 + wid;
      int ldso = __builtin_amdgcn_readfirstlane(blki * 512);
      gload16(Kbh + kt * 16384 + blki * 512 + okl, Ks + ldso);
      gload16(Vbh + blki * 4096 + kt * 256 + ((i & 1) ? ovlo : ovle), Vs + ldso);
    }
    const bool msk = ((fb >> (kt * 2)) & 3) != 0;
    if (msk)
      maddv[t] = (1.0f - (float)mask[b * 2048 + kt * 256 + t]) * (-10000.0f * LOG2E);
    __syncthreads();

    // ---- per-kb fused: QK (4 MFMA) -> exp2 -> pack -> PV (4 MFMA) ----
#pragma unroll
    for (int kb = 0; kb < 8; kb++) {
      const ushort* krow = Ks + (kb * 16 + prq) * 128;   // phys row base
      const f32x16 zz = {};
      __builtin_amdgcn_s_setprio(1);
      bf16x8 kf0 = *(const bf16x8*)(krow + (((0 + hi) | hq8) ^ prq) * 8);
      f32x16 a = __builtin_amdgcn_mfma_f32_32x32x16_bf16(kf0, qf[0], zz, 0, 0, 0);
      bf16x8 kf1 = *(const bf16x8*)(krow + (((2 + hi) | hq8) ^ prq) * 8);
      a = __builtin_amdgcn_mfma_f32_32x32x16_bf16(kf1, qf[1], a, 0, 0, 0);
      bf16x8 kf2 = *(const bf16x8*)(krow + (((4 + hi) | hq8) ^ prq) * 8);
      a = __builtin_amdgcn_mfma_f32_32x32x16_bf16(kf2, qf[2], a, 0, 0, 0);
      bf16x8 kf3 = *(const bf16x8*)(krow + (((6 + hi) | hq8) ^ prq) * 8);
      a = __builtin_amdgcn_mfma_f32_32x32x16_bf16(kf3, qf[3], a, 0, 0, 0);
      __builtin_amdgcn_s_setprio(0);

      if (msk) {
#pragma unroll
        for (int qd = 0; qd < 4; qd++) {
          f32x4 ma = *(const f32x4*)(maddv + kb * 32 + qd * 8 + hi * 4);
#pragma unroll
          for (int rr = 0; rr < 4; rr++) a[qd * 4 + rr] += ma[rr];
        }
      }

#pragma unroll
      for (int w2 = 0; w2 < 2; w2++) {
        const int o = w2 * 8;
        float e0 = __builtin_amdgcn_exp2f(a[o + 0]);
        float e1 = __builtin_amdgcn_exp2f(a[o + 1]);
        float e2 = __builtin_amdgcn_exp2f(a[o + 2]);
        float e3 = __builtin_amdgcn_exp2f(a[o + 3]);
        float e4 = __builtin_amdgcn_exp2f(a[o + 4]);
        float e5 = __builtin_amdgcn_exp2f(a[o + 5]);
        float e6 = __builtin_amdgcn_exp2f(a[o + 6]);
        float e7 = __builtin_amdgcn_exp2f(a[o + 7]);
        l0 += e0; l1 += e1; l0 += e2; l1 += e3;
        l0 += e4; l1 += e5; l0 += e6; l1 += e7;
        unsigned a0, a1, b0, b1;
        asm("v_cvt_pk_bf16_f32 %0, %1, %2" : "=v"(a0) : "v"(e0), "v"(e1));
        asm("v_cvt_pk_bf16_f32 %0, %1, %2" : "=v"(a1) : "v"(e2), "v"(e3));
        asm("v_cvt_pk_bf16_f32 %0, %1, %2" : "=v"(b0) : "v"(e4), "v"(e5));
        asm("v_cvt_pk_bf16_f32 %0, %1, %2" : "=v"(b1) : "v"(e6), "v"(e7));
        asm("v_permlane32_swap_b32 %0, %1" : "+v"(a0), "+v"(b0));
        asm("v_permlane32_swap_b32 %0, %1" : "+v"(a1), "+v"(b1));
        union { unsigned u[4]; bf16x8 v8; } pu;
        pu.u[0] = a0; pu.u[1] = a1; pu.u[2] = b0; pu.u[3] = b1;
        bf16x8 pf = pu.v8;
        int w = kb * 2 + w2;
        __builtin_amdgcn_s_setprio(1);
#pragma unroll
        for (int df = 0; df < 2; df++) {
          int d = df * 32 + l31;
          int c = (w * 2 + hi) ^ (d & 15);
          bf16x8 vf = *(const bf16x8*)(Vs + d * 256 + c * 8);
          cacc[df] = __builtin_amdgcn_mfma_f32_32x32x16_bf16(vf, pf, cacc[df], 0, 0, 0);
        }
        __builtin_amdgcn_s_setprio(0);
      }
    }
    __syncthreads();
  }

  // ---- epilogue: l = in-lane chains + cross-hi partner; ctx^T / l ----
  float lrun = l0 + l1;
  lrun += __shfl_xor(lrun, 32);
  float linv = 1.0f / lrun;
  int qg = qb * 128 + wid * 32 + l31;
  float* op = out + ((size_t)(b * 2048 + qg)) * 1024 + h * 64;
#pragma unroll
  for (int df = 0; df < 2; df++)
#pragma unroll
    for (int qd = 0; qd < 4; qd++) {
      f32x4 v;
      v[0] = cacc[df][qd * 4 + 0] * linv;
      v[1] = cacc[df][qd * 4 + 1] * linv;
      v[2] = cacc[df][qd * 4 + 2] * linv;
      v[3] = cacc[df][qd * 4 + 3] * linv;
      *(f32x4*)(op + df * 32 + qd * 8 + hi * 4) = v;
    }
}

// ---------------------------------------------------------------------------
extern "C" void kernel_launch(void* const* d_in, const int* in_sizes, int n_in,
                              void* d_out, int out_size, void* d_ws, size_t ws_size,
                              hipStream_t stream) {
  const float* x  = (const float*)d_in[0];
  const int* mask = (const int*)d_in[1];
  const float* Wq = (const float*)d_in[2];
  const float* bq = (const float*)d_in[3];
  const float* Wk = (const float*)d_in[4];
  const float* bk = (const float*)d_in[5];
  const float* Wv = (const float*)d_in[6];
  const float* bv = (const float*)d_in[7];
  float* out = (float*)d_out;

  char* ws = (char*)d_ws;
  ushort* xb  = (ushort*)(ws);                                  // 16 MB
  ushort* WT  = (ushort*)(ws + (size_t)16777216);               // 6 MB
  ushort* Qg  = (ushort*)(ws + (size_t)23068672);               // 16 MB
  ushort* Kg  = (ushort*)(ws + (size_t)39845888);               // 16 MB
  ushort* VTg = (ushort*)(ws + (size_t)56623104);               // 16 MB
  int*    flg = (int*)(ws + (size_t)73400320);                  // 16 B

  prep<<<dim3(11265), dim3(256), 0, stream>>>(x, xb, Wq, Wk, Wv, WT, mask, flg);
  gemm_qkv<<<dim3(1536), dim3(256), 0, stream>>>(xb, WT, bq, bk, bv, Qg, Kg, VTg);
  attn_kernel<<<dim3(1024), dim3(256), 0, stream>>>(Qg, Kg, VTg, mask, flg, out);
}

// Round 8
// 158.228 us; speedup vs baseline: 2.1583x; 1.0292x over previous
//
#include <hip/hip_runtime.h>

// ---------------------------------------------------------------------------
// AttentionLayer: out = softmax((xWq+bq)(xWk+bk)^T/8 + mask) (xWv+bv)
// B=4, S=2048, D=1024, H=16, Dh=64.  All-bf16 MFMA pipeline, fp32 accum.
// R22: Q-IN-LDS on the R19 body.  qf[4] (16 persistent arch VGPRs) is
//      replaced by per-kb ds_reads from a dedicated Qs buffer (same
//      pair-interleave layout; slot formula is IDENTICAL to kf's, so zero
//      new address math).  Rationale: R19 measured 2 blocks/CU resident
//      despite (256,3)'s 170-total cap and LDS room for 4 => total alloc
//      (80 arch + ~96 acc-side) sits JUST above the 3-block threshold.
//      -16 arch flips the cliff: 3 blocks/CU (+50% TLP) at LDS 49KB
//      (3x49.7=149<=160).  Also deletes both prologue barriers (Qs is
//      never overwritten; Q staging drains at the first loop barrier).
// LAWS: R21 KVBLK=256: VGPR 80->128, occ 19.7, -18% => bigger tiles cost
//      regs; phase fixed-costs not the stall.  R20 zero-LDS = 3x WORSE
//      (L2 latency in MFMA chain at 2 waves/SIMD) => staging load-bearing.
//      R19 diet landed (80) but 2 blocks still.  R15 reg-staging SPILLS;
//      R16 dbuf -5%; R17 T15 -3%; R18 wide-Q SPILLS -32%; 7 scheduling
//      variants null/neg; bound(256,4)=>spill; reuse=2=>spill.
//      => residency cliff is the last open lever; attack per-wave ARCH
//      state only, never add state.
// ---------------------------------------------------------------------------

typedef __attribute__((ext_vector_type(8))) short bf16x8;
typedef __attribute__((ext_vector_type(4))) float f32x4;
typedef __attribute__((ext_vector_type(16))) float f32x16;

#define LOG2E 1.4426950408889634f

__device__ __forceinline__ ushort f2bf(float f) {
  union { float f; unsigned int u; } x; x.f = f;
  unsigned int r = x.u + 0x7fffu + ((x.u >> 16) & 1u);   // RNE
  return (ushort)(r >> 16);
}

// async global->LDS, 16B per lane; LDS dest = wave-uniform base + lane*16
__device__ __forceinline__ void gload16(const ushort* g, ushort* l) {
  __builtin_amdgcn_global_load_lds(
      (__attribute__((address_space(1))) unsigned int*)(g),
      (__attribute__((address_space(3))) unsigned int*)(l), 16, 0, 0);
}

// ---------------------------------------------------------------------------
// prep: blocks 0..8191 = x->bf16; 8192..11263 = W transpose; 11264 = mask scan
__global__ __launch_bounds__(256) void prep(
    const float* __restrict__ x, ushort* __restrict__ xb,
    const float* __restrict__ Wq, const float* __restrict__ Wk,
    const float* __restrict__ Wv, ushort* __restrict__ WT,
    const int* __restrict__ mask, int* __restrict__ flagw) {
  __shared__ float tile[32][33];
  __shared__ int accum[64];
  const int blk = blockIdx.x, t = threadIdx.x;
  if (blk < 8192) {
    int i = blk * 256 + t;
    float4 v = ((const float4*)x)[i];
    ushort4 o;
    o.x = f2bf(v.x); o.y = f2bf(v.y); o.z = f2bf(v.z); o.w = f2bf(v.w);
    ((ushort4*)xb)[i] = o;
  } else if (blk < 11264) {
    int bb = blk - 8192;
    int z = bb >> 10, rem = bb & 1023, db = rem >> 5, nb = rem & 31;
    const float* W = (z == 0) ? Wq : ((z == 1) ? Wk : Wv);
    int tx = t & 31, ty = t >> 5;   // 32 x 8
#pragma unroll
    for (int i = 0; i < 4; i++) {
      int dl = ty + i * 8;
      tile[dl][tx] = W[(size_t)(db * 32 + dl) * 1024 + nb * 32 + tx];
    }
    __syncthreads();
#pragma unroll
    for (int i = 0; i < 4; i++) {
      int nl = ty + i * 8;
      WT[(size_t)(z * 1024 + nb * 32 + nl) * 1024 + db * 32 + tx] = f2bf(tile[tx][nl]);
    }
  } else {
    if (t < 64) accum[t] = 0;
    __syncthreads();
    int p = t >> 2, j = t & 3;          // p = b*16+kt
    int base = p * 128 + j * 32;
    int s = 0;
#pragma unroll
    for (int i = 0; i < 8; i++) {
      int4 v = *(const int4*)(mask + base + i * 4);
      s += v.x + v.y + v.z + v.w;
    }
    atomicAdd(&accum[p], s);
    __syncthreads();
    if (t < 4) {
      int w = 0;
#pragma unroll
      for (int kt = 0; kt < 16; kt++)
        if (accum[t * 16 + kt] != 128) w |= (1 << kt);
      flagw[t] = w;
    }
  }
}

// ---------------------------------------------------------------------------
// fused QKV GEMM, m97 structure + early-issue staging (R8 version, (256,2)).
// blocks 0..1023: mode0 (Q,K: M=8192 N=2048); 1024..1535: mode1 (V^T).
__global__ __launch_bounds__(256, 2) void gemm_qkv(
    const ushort* __restrict__ xb, const ushort* __restrict__ WT,
    const float* __restrict__ bq, const float* __restrict__ bk,
    const float* __restrict__ bv, ushort* __restrict__ Qg,
    ushort* __restrict__ Kg, ushort* __restrict__ VTg) {
  __shared__ __align__(16) ushort As[128 * 64];
  __shared__ __align__(16) ushort Bs[128 * 64];
  const int t = threadIdx.x, wid = t >> 6, lane = t & 63;
  const int blk = blockIdx.x;
  int mode, mb, nb;
  const ushort *A, *B;
  if (blk < 1024) {
    mode = 0;
    int lin2 = (blk & 7) * 128 + (blk >> 3);   // XCD owns 8 mb-panels
    nb = lin2 & 15; mb = lin2 >> 4;
    A = xb; B = WT;
  } else {
    mode = 1;
    int l = blk - 1024;
    int lin2 = (l & 7) * 64 + (l >> 3);        // XCD owns 8 nb-panels
    mb = lin2 & 7; nb = lin2 >> 3;
    A = WT + (size_t)2048 * 1024; B = xb;
  }
  const ushort* Ab = A + (size_t)mb * 128 * 1024;
  const ushort* Bb = B + (size_t)nb * 128 * 1024;
  const int wr = wid >> 1, wc = wid & 1;

  f32x4 acc[4][4] = {};

  const int srow = lane >> 3;              // 0..7 row-in-8
  const int schunk = (lane & 7) ^ srow;    // pre-swizzled source chunk

  // prologue: issue stage(0)
#pragma unroll
  for (int i = 0; i < 4; i++) {
    int blki = i * 4 + wid;
    int row = blki * 8 + srow;
    int ldso = __builtin_amdgcn_readfirstlane(blki * 512);
    gload16(Ab + (size_t)row * 1024 + schunk * 8, As + ldso);
    gload16(Bb + (size_t)row * 1024 + schunk * 8, Bs + ldso);
  }

  for (int kt = 0; kt < 16; ++kt) {
    __syncthreads();                       // (1) stage(kt) arrived

    bf16x8 af[2][4], bf[2][4];
#pragma unroll
    for (int ks = 0; ks < 2; ks++) {
#pragma unroll
      for (int m = 0; m < 4; m++) {
        int row = wr * 64 + m * 16 + (lane & 15);
        int slot = (ks * 4 + (lane >> 4)) ^ (row & 7);
        af[ks][m] = *(const bf16x8*)(As + row * 64 + slot * 8);
      }
#pragma unroll
      for (int n = 0; n < 4; n++) {
        int row = wc * 64 + n * 16 + (lane & 15);
        int slot = (ks * 4 + (lane >> 4)) ^ (row & 7);
        bf[ks][n] = *(const bf16x8*)(Bs + row * 64 + slot * 8);
      }
    }
    __syncthreads();                       // (2) all fragment reads in regs

    if (kt < 15) {
      const int kof = (kt + 1) * 64 + schunk * 8;
#pragma unroll
      for (int i = 0; i < 4; i++) {
        int blki = i * 4 + wid;
        int row = blki * 8 + srow;
        int ldso = __builtin_amdgcn_readfirstlane(blki * 512);
        gload16(Ab + (size_t)row * 1024 + kof, As + ldso);
        gload16(Bb + (size_t)row * 1024 + kof, Bs + ldso);
      }
    }

#pragma unroll
    for (int ks = 0; ks < 2; ks++)
#pragma unroll
      for (int m = 0; m < 4; m++)
#pragma unroll
        for (int n = 0; n < 4; n++)
          acc[m][n] = __builtin_amdgcn_mfma_f32_16x16x32_bf16(
              af[ks][m], bf[ks][n], acc[m][n], 0, 0, 0);
  }

  // epilogue
#pragma unroll
  for (int m = 0; m < 4; m++) {
#pragma unroll
    for (int n = 0; n < 4; n++) {
      if (mode == 0) {
        int col = nb * 128 + wc * 64 + n * 16 + (lane & 15);  // n: [Q|K] 0..2047
        int wq = col >> 10;                                   // 0=Q 1=K
        float bs = wq ? bk[col & 1023] : bq[col & 1023];
        float scale = wq ? 1.0f : (0.125f * LOG2E);           // fold log2e into Q
        ushort* dst = wq ? Kg : Qg;
        int h = (col >> 6) & 15, d = col & 63;
#pragma unroll
        for (int r = 0; r < 4; r++) {
          int row = mb * 128 + wr * 64 + m * 16 + (lane >> 4) * 4 + r;  // b*2048+s
          int b = row >> 11, s = row & 2047;
          float v = (acc[m][n][r] + bs) * scale;
          dst[((size_t)((b << 4) + h) * 2048 + s) * 64 + d] = f2bf(v);
        }
      } else {
        int col = nb * 128 + wc * 64 + n * 16 + (lane & 15);  // m-index: b*2048+s
        int b = col >> 11, s = col & 2047;
#pragma unroll
        for (int r = 0; r < 4; r++) {
          int p = mb * 128 + wr * 64 + m * 16 + (lane >> 4) * 4 + r;  // h*64+d
          float v = acc[m][n][r] + bv[p];
          int h = p >> 6, d = p & 63;
          VTg[((size_t)((b << 4) + h) * 64 + d) * 2048 + s] = f2bf(v);
        }
      }
    }
  }
}

// ---------------------------------------------------------------------------
// Flash attention (R22 = R19 body + Q-in-LDS): swapped-operand 32x32 MFMA,
// single-buffer 2-phase loop, per-kb fused QK->exp->pack->PV, max-free
// softmax, XCD swizzle, K/Q pair-interleave LDS mapping.  Q lives in its
// own Qs buffer (never overwritten) and is re-read per kb with the SAME
// slot offsets as kf => -16 persistent arch VGPRs, 0 new address math,
// both prologue barriers deleted.
__global__ __launch_bounds__(256, 3) void attn_kernel(
    const ushort* __restrict__ Qg, const ushort* __restrict__ Kg,
    const ushort* __restrict__ VTg, const int* __restrict__ mask,
    const int* __restrict__ flagw, float* __restrict__ out) {
  __shared__ __align__(16) ushort Qs[128 * 64];   // 16KB; 64 phys rows x 256B
  __shared__ __align__(16) ushort Ks[128 * 64];   // 16KB; 64 phys rows x 256B
  __shared__ __align__(16) ushort Vs[64 * 128];   // 16KB; rows=d, 4-bit swizzle
  __shared__ float maddv[128];

  const int t = threadIdx.x, wid = t >> 6, lane = t & 63;
  const int l31 = lane & 31, hi = lane >> 5;
  const int lin = blockIdx.x;
  const int lin2 = (lin & 7) * 128 + (lin >> 3);   // bijective XCD chunking
  const int qb = lin2 & 15, bh = lin2 >> 4;
  const int b = bh >> 4, h = bh & 15;
  const ushort* Qbh = Qg + ((size_t)bh * 2048 + qb * 128) * 64;
  const ushort* Kbh = Kg + (size_t)bh * 2048 * 64;
  const ushort* Vbh = VTg + (size_t)bh * 64 * 2048;

  // ---- staging lane constants (pair-interleave inverse map, collapsed) ----
  const int pr_l = lane >> 4;                 // 0..3 within issue
  const int s_l = lane & 15;
  const int spk = s_l ^ (4 * wid + pr_l);     // shared by Q, K, V staging
  const int okl = 128 * pr_l + (spk >> 3) * 64 + (spk & 7) * 8;
  const int ovl = 2048 * pr_l + spk * 8;

  // ---- fragment-read lane constants ----
  const int prq = l31 >> 1;                   // phys row in 16-row group (0..15)
  const int hq8 = (l31 & 1) << 3;             // halfq<<3

  // ---- prologue: stage Q tile into Qs (pair-interleaved); NO barrier ----
  // (Qs is never overwritten; drains at the first loop barrier)
#pragma unroll
  for (int i = 0; i < 4; i++) {
    int blki = i * 4 + wid;
    int ldso = __builtin_amdgcn_readfirstlane(blki * 512);
    gload16(Qbh + blki * 512 + okl, Qs + ldso);
  }
  const int fb = flagw[b];            // per-tile mask bits (uniform)
  const ushort* qbase = Qs + (wid * 16 + prq) * 128;   // per-wave Q phys rows

  f32x16 cacc[2] = {};
  float l0 = 0.f, l1 = 0.f;           // persistent psum chains

  for (int kt = 0; kt < 16; ++kt) {
    // ---- stage K (pair-interleaved) and VT [64][128], 8 issues/wave ----
#pragma unroll
    for (int i = 0; i < 4; i++) {
      int blki = i * 4 + wid;
      int ldso = __builtin_amdgcn_readfirstlane(blki * 512);
      gload16(Kbh + kt * 8192 + blki * 512 + okl, Ks + ldso);
      gload16(Vbh + blki * 8192 + kt * 128 + ovl, Vs + ldso);
    }
    const bool msk = ((fb >> kt) & 1) != 0;
    if (msk && t < 128)
      maddv[t] = (1.0f - (float)mask[b * 2048 + kt * 128 + t]) * (-10000.0f * LOG2E);
    __syncthreads();

    // ---- per-kb fused: QK (4 MFMA) -> exp2 -> pack -> PV (4 MFMA) ----
#pragma unroll
    for (int kb = 0; kb < 4; kb++) {
      const ushort* krow = Ks + (kb * 16 + prq) * 128;   // phys row base
      const f32x16 zz = {};
      const int o0 = (((0 + hi) | hq8) ^ prq) * 8;
      const int o1 = (((2 + hi) | hq8) ^ prq) * 8;
      const int o2 = (((4 + hi) | hq8) ^ prq) * 8;
      const int o3 = (((6 + hi) | hq8) ^ prq) * 8;
      __builtin_amdgcn_s_setprio(1);
      bf16x8 kf0 = *(const bf16x8*)(krow + o0);
      bf16x8 q0 = *(const bf16x8*)(qbase + o0);
      f32x16 a = __builtin_amdgcn_mfma_f32_32x32x16_bf16(kf0, q0, zz, 0, 0, 0);
      bf16x8 kf1 = *(const bf16x8*)(krow + o1);
      bf16x8 q1 = *(const bf16x8*)(qbase + o1);
      a = __builtin_amdgcn_mfma_f32_32x32x16_bf16(kf1, q1, a, 0, 0, 0);
      bf16x8 kf2 = *(const bf16x8*)(krow + o2);
      bf16x8 q2 = *(const bf16x8*)(qbase + o2);
      a = __builtin_amdgcn_mfma_f32_32x32x16_bf16(kf2, q2, a, 0, 0, 0);
      bf16x8 kf3 = *(const bf16x8*)(krow + o3);
      bf16x8 q3 = *(const bf16x8*)(qbase + o3);
      a = __builtin_amdgcn_mfma_f32_32x32x16_bf16(kf3, q3, a, 0, 0, 0);
      __builtin_amdgcn_s_setprio(0);

      if (msk) {
#pragma unroll
        for (int qd = 0; qd < 4; qd++) {
          f32x4 ma = *(const f32x4*)(maddv + kb * 32 + qd * 8 + hi * 4);
#pragma unroll
          for (int rr = 0; rr < 4; rr++) a[qd * 4 + rr] += ma[rr];
        }
      }

#pragma unroll
      for (int w2 = 0; w2 < 2; w2++) {
        const int o = w2 * 8;
        float e0 = __builtin_amdgcn_exp2f(a[o + 0]);
        float e1 = __builtin_amdgcn_exp2f(a[o + 1]);
        float e2 = __builtin_amdgcn_exp2f(a[o + 2]);
        float e3 = __builtin_amdgcn_exp2f(a[o + 3]);
        float e4 = __builtin_amdgcn_exp2f(a[o + 4]);
        float e5 = __builtin_amdgcn_exp2f(a[o + 5]);
        float e6 = __builtin_amdgcn_exp2f(a[o + 6]);
        float e7 = __builtin_amdgcn_exp2f(a[o + 7]);
        l0 += e0; l1 += e1; l0 += e2; l1 += e3;
        l0 += e4; l1 += e5; l0 += e6; l1 += e7;
        unsigned a0, a1, b0, b1;
        asm("v_cvt_pk_bf16_f32 %0, %1, %2" : "=v"(a0) : "v"(e0), "v"(e1));
        asm("v_cvt_pk_bf16_f32 %0, %1, %2" : "=v"(a1) : "v"(e2), "v"(e3));
        asm("v_cvt_pk_bf16_f32 %0, %1, %2" : "=v"(b0) : "v"(e4), "v"(e5));
        asm("v_cvt_pk_bf16_f32 %0, %1, %2" : "=v"(b1) : "v"(e6), "v"(e7));
        asm("v_permlane32_swap_b32 %0, %1" : "+v"(a0), "+v"(b0));
        asm("v_permlane32_swap_b32 %0, %1" : "+v"(a1), "+v"(b1));
        union { unsigned u[4]; bf16x8 v8; } pu;
        pu.u[0] = a0; pu.u[1] = a1; pu.u[2] = b0; pu.u[3] = b1;
        bf16x8 pf = pu.v8;
        int w = kb * 2 + w2;
        __builtin_amdgcn_s_setprio(1);
#pragma unroll
        for (int df = 0; df < 2; df++) {
          int d = df * 32 + l31;
          int c = (w * 2 + hi) ^ (d & 15);
          bf16x8 vf = *(const bf16x8*)(Vs + d * 128 + c * 8);
          cacc[df] = __builtin_amdgcn_mfma_f32_32x32x16_bf16(vf, pf, cacc[df], 0, 0, 0);
        }
        __builtin_amdgcn_s_setprio(0);
      }
    }
    __syncthreads();
  }

  // ---- epilogue: l = in-lane chains + cross-hi partner; ctx^T / l ----
  float lrun = l0 + l1;
  lrun += __shfl_xor(lrun, 32);
  float linv = 1.0f / lrun;
  int qg = qb * 128 + wid * 32 + l31;
  float* op = out + ((size_t)(b * 2048 + qg)) * 1024 + h * 64;
#pragma unroll
  for (int df = 0; df < 2; df++)
#pragma unroll
    for (int qd = 0; qd < 4; qd++) {
      f32x4 v;
      v[0] = cacc[df][qd * 4 + 0] * linv;
      v[1] = cacc[df][qd * 4 + 1] * linv;
      v[2] = cacc[df][qd * 4 + 2] * linv;
      v[3] = cacc[df][qd * 4 + 3] * linv;
      *(f32x4*)(op + df * 32 + qd * 8 + hi * 4) = v;
    }
}

// ---------------------------------------------------------------------------
extern "C" void kernel_launch(void* const* d_in, const int* in_sizes, int n_in,
                              void* d_out, int out_size, void* d_ws, size_t ws_size,
                              hipStream_t stream) {
  const float* x  = (const float*)d_in[0];
  const int* mask = (const int*)d_in[1];
  const float* Wq = (const float*)d_in[2];
  const float* bq = (const float*)d_in[3];
  const float* Wk = (const float*)d_in[4];
  const float* bk = (const float*)d_in[5];
  const float* Wv = (const float*)d_in[6];
  const float* bv = (const float*)d_in[7];
  float* out = (float*)d_out;

  char* ws = (char*)d_ws;
  ushort* xb  = (ushort*)(ws);                                  // 16 MB
  ushort* WT  = (ushort*)(ws + (size_t)16777216);               // 6 MB
  ushort* Qg  = (ushort*)(ws + (size_t)23068672);               // 16 MB
  ushort* Kg  = (ushort*)(ws + (size_t)39845888);               // 16 MB
  ushort* VTg = (ushort*)(ws + (size_t)56623104);               // 16 MB
  int*    flg = (int*)(ws + (size_t)73400320);                  // 16 B

  prep<<<dim3(11265), dim3(256), 0, stream>>>(x, xb, Wq, Wk, Wv, WT, mask, flg);
  gemm_qkv<<<dim3(1536), dim3(256), 0, stream>>>(xb, WT, bq, bk, bv, Qg, Kg, VTg);
  attn_kernel<<<dim3(1024), dim3(256), 0, stream>>>(Qg, Kg, VTg, mask, flg, out);
}